// Round 4
// baseline (248.166 us; speedup 1.0000x reference)
//
#include <hip/hip_runtime.h>
#include <math.h>

#define NCLS 5
#define NBINS 25
#define NTHREADS 256
#define NBLOCKS 768              // 3 blocks/CU (LDS-capped), 12 waves/CU
#define ROWS 128                 // rows per wave-chunk
#define DEPTH 4                  // chunks in flight per wave (3 ahead + current)
#define CHUNK_F4 160             // 128 rows * 5 floats / 4
#define LPC 4                    // vmcnt events per stage: 2 full + 2 masked

// global -> LDS direct copy, 16B per active lane. LDS dest = wave-uniform
// base (HW adds lane*16 for ACTIVE lanes); global src is per-lane.
__device__ __forceinline__ void gload_lds16(const void* g, void* l) {
    __builtin_amdgcn_global_load_lds(
        (const __attribute__((address_space(1))) unsigned int*)(const unsigned int*)g,
        (__attribute__((address_space(3))) unsigned int*)(unsigned int*)l,
        16, 0, 0);
}

// Kernel 1: wave-private LDS staging, barrier-free, DEPTH-4 pipeline.
// Round-3 post-mortem: depth-1 prefetch left each wave latency-bound
// (wait ~600cy per 6KB chunk). Here 3 chunks stay in flight ahead of
// compute (vmcnt(12) steady-state, tail drains 8->4->0), so sustained
// per-CU outstanding bytes (~12 waves x 9-12KB) exceed BW*latency and
// the period is set by HBM supply.
// LDS reads: row = lane + 64*rr -> float idx 5*lane+c, gcd(5,32)=1 ->
// conflict-free. Per-wave histograms, no cross-wave atomics.
__global__ void __launch_bounds__(NTHREADS)
kappa_count(const float* __restrict__ preds,
            const int* __restrict__ truev,
            int N,
            unsigned int* __restrict__ partials) {
    __shared__ float s_pred[DEPTH][4][ROWS * NCLS];  // 40 KiB
    __shared__ int   s_lab [DEPTH][4][ROWS];         // 8 KiB
    __shared__ unsigned int s_conf[4 * 32];          // per-wave hists

    const int tid = threadIdx.x;
    const int wv = tid >> 6;
    const int lane = tid & 63;
    if (tid < 128) s_conf[tid] = 0u;
    __syncthreads();
    unsigned int* hist = &s_conf[wv << 5];

    const int nchunks = N / ROWS;
    const int wgid = blockIdx.x * 4 + wv;            // global wave id
    const int wstride = gridDim.x * 4;

    auto stage = [&](int c, int b) {
        const float4* sp = (const float4*)preds + (size_t)c * CHUNK_F4;
        gload_lds16(sp + lane,       &s_pred[b][wv][0]);    // floats 0..255
        gload_lds16(sp + 64 + lane,  &s_pred[b][wv][256]);  // floats 256..511
        if (lane < 32) {                                    // half segments
            gload_lds16(sp + 128 + lane, &s_pred[b][wv][512]);  // 512..639
            gload_lds16((const int4*)truev + (size_t)c * 32 + lane,
                        &s_lab[b][wv][0]);                  // 128 labels
        }
    };

    auto dorow = [&](float r0, float r1, float r2, float r3, float r4, int t) {
        // arithmetic kept expression-identical to the verified round-0 kernel
        float m = fmaxf(fmaxf(fmaxf(fmaxf(r0, r1), r2), r3), r4);
        float e0 = __expf(r0 - m), e1 = __expf(r1 - m), e2 = __expf(r2 - m),
              e3 = __expf(r3 - m), e4 = __expf(r4 - m);
        float s = e0 + e1 + e2 + e3 + e4;
        float dot = e1 + e2 * 2.f + e3 * 3.f + e4 * 4.f;
        int pi = (int)rintf(dot / s);          // round-half-even == jnp.round
        pi = min(max(pi, 0), NCLS - 1);
        atomicAdd(&hist[t * NCLS + pi], 1u);
    };

    auto compute = [&](int b) {
        const float* bp = s_pred[b][wv];
        const int* lp = s_lab[b][wv];
        #pragma unroll
        for (int rr = 0; rr < 2; ++rr) {
            const int r = lane + (rr << 6);
            const float* rp = bp + r * NCLS;
            dorow(rp[0], rp[1], rp[2], rp[3], rp[4], lp[r]);
        }
    };

    int c = wgid;
    int cb = 0;
    #pragma unroll
    for (int k = 0; k < DEPTH - 1; ++k) {            // prologue: 3 ahead
        const int ck = c + k * wstride;
        if (ck < nchunks) stage(ck, k);
    }

    // steady state: always 4 chunks outstanding, wait to 12 -> chunk c ready
    for (; c + (DEPTH - 1) * wstride < nchunks; c += wstride) {
        stage(c + (DEPTH - 1) * wstride, (cb + DEPTH - 1) & 3);
        asm volatile("s_waitcnt vmcnt(12)" ::: "memory");
        compute(cb);
        cb = (cb + 1) & 3;
    }

    // tail: remaining chunks already staged; drain 8 -> 4 -> 0
    int rem = 0;
    for (int cc = c; cc < nchunks; cc += wstride) rem++;
    for (; c < nchunks; c += wstride) {
        rem--;
        if (rem >= 2)      asm volatile("s_waitcnt vmcnt(8)" ::: "memory");
        else if (rem == 1) asm volatile("s_waitcnt vmcnt(4)" ::: "memory");
        else               asm volatile("s_waitcnt vmcnt(0)" ::: "memory");
        compute(cb);
        cb = (cb + 1) & 3;
    }

    // tail rows (N % 128 != 0; N=8M divisible — kept for safety)
    if (blockIdx.x == 0 && wv == 0) {
        for (int r = nchunks * ROWS + lane; r < N; r += 64) {
            float v0 = preds[(size_t)r * NCLS + 0];
            float v1 = preds[(size_t)r * NCLS + 1];
            float v2 = preds[(size_t)r * NCLS + 2];
            float v3 = preds[(size_t)r * NCLS + 3];
            float v4 = preds[(size_t)r * NCLS + 4];
            dorow(v0, v1, v2, v3, v4, truev[r]);
        }
    }

    __syncthreads();
    // bin-major (transposed) partials: partials[bin][block]
    if (tid < NBINS)
        partials[(size_t)tid * gridDim.x + blockIdx.x] =
            s_conf[tid] + s_conf[32 + tid] + s_conf[64 + tid] + s_conf[96 + tid];
}

// Kernel 2: bin-major reduction. 32 lanes per bin, coalesced reads,
// shuffle reduce, then O(25) kappa math in double.
__global__ void kappa_final(const unsigned int* __restrict__ partials,
                            int nb,
                            float* __restrict__ out) {
    __shared__ double s_bin[NBINS];
    const int tid = threadIdx.x;
    const int bin = tid >> 5;
    const int l = tid & 31;

    if (bin < NBINS) {
        unsigned int acc = 0u;                 // total 8M fits u32
        const unsigned int* p = partials + (size_t)bin * nb;
        for (int j = l; j < nb; j += 32) acc += p[j];
        #pragma unroll
        for (int off = 16; off > 0; off >>= 1)
            acc += __shfl_down(acc, off, 32);
        if (l == 0) s_bin[bin] = (double)acc;
    }
    __syncthreads();

    if (tid == 0) {
        double tot = 0.0;
        for (int i = 0; i < NBINS; i++) tot += s_bin[i];
        double th[NCLS] = {0, 0, 0, 0, 0};
        double ph[NCLS] = {0, 0, 0, 0, 0};
        for (int i = 0; i < NCLS; i++)
            for (int j = 0; j < NCLS; j++) {
                th[i] += s_bin[i * NCLS + j];
                ph[j] += s_bin[i * NCLS + j];
            }
        double num = 0.0, den = 0.0;
        for (int i = 0; i < NCLS; i++)
            for (int j = 0; j < NCLS; j++) {
                double w = (double)((i - j) * (i - j)) / 16.0;  // (C-1)^2 = 16
                num += w * s_bin[i * NCLS + j];
                den += w * th[i] * ph[j];
            }
        out[0] = (float)(num * tot / den);     // (num/tot)/(den/tot^2)
    }
}

extern "C" void kernel_launch(void* const* d_in, const int* in_sizes, int n_in,
                              void* d_out, int out_size, void* d_ws, size_t ws_size,
                              hipStream_t stream) {
    const float* preds = (const float*)d_in[0];
    const int* truev = (const int*)d_in[1];
    const int N = in_sizes[1];  // number of samples (true is [N])

    int nblocks = NBLOCKS;
    size_t need = (size_t)nblocks * NBINS * sizeof(unsigned int);
    if (need > ws_size) nblocks = (int)(ws_size / (NBINS * sizeof(unsigned int)));
    unsigned int* partials = (unsigned int*)d_ws;

    kappa_count<<<nblocks, NTHREADS, 0, stream>>>(preds, truev, N, partials);
    kappa_final<<<1, 1024, 0, stream>>>(partials, nblocks, (float*)d_out);
}